// Round 2
// baseline (516.421 us; speedup 1.0000x reference)
//
#include <hip/hip_runtime.h>

// CRPS loss, mean reduction.
// forecasts: (N=20, M) f32 where M = B*C*D*H*W; target: (M,) f32; out: scalar f32.
// crps(m) = (1/N) sum_i |x_i - y| - (1/N^2) sum_{i<j} |x_i - x_j|
// out = mean_m crps(m)
//
// R2: float2 per thread (was float4) -> x[2][20] = 40 VGPRs, forced 8 waves/EU
// via __launch_bounds__(256,8). Streaming kernel: occupancy is the BW lever.

constexpr int NS = 20;          // sample count (compile-time for full unroll)
constexpr int BLOCK = 256;

__global__ __launch_bounds__(BLOCK, 8) void crps_partial_kernel(
    const float* __restrict__ forecasts,
    const float* __restrict__ target,
    float* __restrict__ partial,   // one float per block
    int M2)                        // M/2 (positions in float2 units)
{
    const int idx = blockIdx.x * BLOCK + threadIdx.x;
    float local = 0.0f;

    if (idx < M2) {
        const float2* __restrict__ f2 = reinterpret_cast<const float2*>(forecasts);
        const float2* __restrict__ t2 = reinterpret_cast<const float2*>(target);

        // 20 samples x 2 consecutive positions. Lane i reads 8B at base+i*8
        // -> one 512B wave transaction per sample row. All 20 loads issued
        // before first use; vmcnt drains incrementally during compute.
        float x0[NS], x1[NS];
        #pragma unroll
        for (int i = 0; i < NS; ++i) {
            float2 v = f2[(size_t)i * (size_t)M2 + idx];
            x0[i] = v.x; x1[i] = v.y;
        }
        float2 tv = t2[idx];

        float first = 0.0f;
        #pragma unroll
        for (int i = 0; i < NS; ++i)
            first += fabsf(x0[i] - tv.x) + fabsf(x1[i] - tv.y);

        float pair = 0.0f;
        #pragma unroll
        for (int i = 0; i < NS; ++i)
            #pragma unroll
            for (int j = i + 1; j < NS; ++j)
                pair += fabsf(x0[i] - x0[j]) + fabsf(x1[i] - x1[j]);

        local = first * (1.0f / NS) - pair * (1.0f / (NS * NS));
    }

    // Wave (64-lane) shuffle reduce, then cross-wave via LDS.
    #pragma unroll
    for (int off = 32; off > 0; off >>= 1)
        local += __shfl_down(local, off, 64);

    __shared__ float wsum[BLOCK / 64];
    const int lane = threadIdx.x & 63;
    const int wid  = threadIdx.x >> 6;
    if (lane == 0) wsum[wid] = local;
    __syncthreads();
    if (threadIdx.x == 0) {
        float s = 0.0f;
        #pragma unroll
        for (int w = 0; w < BLOCK / 64; ++w) s += wsum[w];
        partial[blockIdx.x] = s;
    }
}

__global__ __launch_bounds__(BLOCK) void crps_final_kernel(
    const float* __restrict__ partial,
    int nblocks,
    float* __restrict__ out,
    float invM)
{
    // Deterministic: fixed per-thread accumulation order + fixed tree reduce.
    float s = 0.0f;
    for (int i = threadIdx.x; i < nblocks; i += BLOCK)
        s += partial[i];

    #pragma unroll
    for (int off = 32; off > 0; off >>= 1)
        s += __shfl_down(s, off, 64);

    __shared__ float wsum[BLOCK / 64];
    const int lane = threadIdx.x & 63;
    const int wid  = threadIdx.x >> 6;
    if (lane == 0) wsum[wid] = s;
    __syncthreads();
    if (threadIdx.x == 0) {
        float tot = 0.0f;
        #pragma unroll
        for (int w = 0; w < BLOCK / 64; ++w) tot += wsum[w];
        out[0] = tot * invM;
    }
}

extern "C" void kernel_launch(void* const* d_in, const int* in_sizes, int n_in,
                              void* d_out, int out_size, void* d_ws, size_t ws_size,
                              hipStream_t stream) {
    const float* forecasts = (const float*)d_in[0];
    const float* target    = (const float*)d_in[1];
    float* out = (float*)d_out;
    float* partial = (float*)d_ws;

    const int M  = in_sizes[1];          // B*C*D*H*W = 3,145,728
    const int M2 = M >> 1;               // divisible by 2 (W=256)
    const int nblocks = (M2 + BLOCK - 1) / BLOCK;   // 6144

    crps_partial_kernel<<<nblocks, BLOCK, 0, stream>>>(forecasts, target, partial, M2);
    crps_final_kernel<<<1, BLOCK, 0, stream>>>(partial, nblocks, out, 1.0f / (float)M);
}

// Round 3
// 61.316 us; speedup vs baseline: 8.4222x; 8.4222x over previous
//
#include <hip/hip_runtime.h>

// CRPS loss, mean reduction.
// forecasts: (N=20, M) f32 where M = B*C*D*H*W; target: (M,) f32; out: scalar f32.
// crps(m) = (1/N) sum_i |x_i - y| - (1/N^2) sum_{i<j} |x_i - x_j|
// out = mean_m crps(m)
//
// R3: one position per thread. x[20] = 20 data VGPRs -> fits the 64-VGPR /
// 8-waves-per-SIMD budget WITHOUT spilling (R2's float2 + forced bounds
// spilled to scratch: VGPR=32, 1GB scratch writes, 516us). Scalar dword
// loads are fully coalesced (256B/wave, adjacent waves adjacent segments).

constexpr int NS = 20;          // sample count (compile-time for full unroll)
constexpr int BLOCK = 256;

__global__ __launch_bounds__(BLOCK, 8) void crps_partial_kernel(
    const float* __restrict__ forecasts,
    const float* __restrict__ target,
    float* __restrict__ partial,   // one float per block
    int M)                         // positions
{
    const int idx = blockIdx.x * BLOCK + threadIdx.x;
    float local = 0.0f;

    if (idx < M) {
        // 20 strided sample loads, one dword per lane. All issued before
        // first use; vmcnt drains incrementally during compute.
        float x[NS];
        #pragma unroll
        for (int i = 0; i < NS; ++i)
            x[i] = forecasts[(size_t)i * (size_t)M + idx];
        const float tv = target[idx];

        float first = 0.0f;
        #pragma unroll
        for (int i = 0; i < NS; ++i)
            first += fabsf(x[i] - tv);

        float pair = 0.0f;
        #pragma unroll
        for (int i = 0; i < NS; ++i)
            #pragma unroll
            for (int j = i + 1; j < NS; ++j)
                pair += fabsf(x[i] - x[j]);

        local = first * (1.0f / NS) - pair * (1.0f / (NS * NS));
    }

    // Wave (64-lane) shuffle reduce, then cross-wave via LDS.
    #pragma unroll
    for (int off = 32; off > 0; off >>= 1)
        local += __shfl_down(local, off, 64);

    __shared__ float wsum[BLOCK / 64];
    const int lane = threadIdx.x & 63;
    const int wid  = threadIdx.x >> 6;
    if (lane == 0) wsum[wid] = local;
    __syncthreads();
    if (threadIdx.x == 0) {
        float s = 0.0f;
        #pragma unroll
        for (int w = 0; w < BLOCK / 64; ++w) s += wsum[w];
        partial[blockIdx.x] = s;
    }
}

__global__ __launch_bounds__(BLOCK) void crps_final_kernel(
    const float* __restrict__ partial,
    int nblocks,
    float* __restrict__ out,
    float invM)
{
    // Deterministic: fixed per-thread accumulation order + fixed tree reduce.
    float s = 0.0f;
    for (int i = threadIdx.x; i < nblocks; i += BLOCK)
        s += partial[i];

    #pragma unroll
    for (int off = 32; off > 0; off >>= 1)
        s += __shfl_down(s, off, 64);

    __shared__ float wsum[BLOCK / 64];
    const int lane = threadIdx.x & 63;
    const int wid  = threadIdx.x >> 6;
    if (lane == 0) wsum[wid] = s;
    __syncthreads();
    if (threadIdx.x == 0) {
        float tot = 0.0f;
        #pragma unroll
        for (int w = 0; w < BLOCK / 64; ++w) tot += wsum[w];
        out[0] = tot * invM;
    }
}

extern "C" void kernel_launch(void* const* d_in, const int* in_sizes, int n_in,
                              void* d_out, int out_size, void* d_ws, size_t ws_size,
                              hipStream_t stream) {
    const float* forecasts = (const float*)d_in[0];
    const float* target    = (const float*)d_in[1];
    float* out = (float*)d_out;
    float* partial = (float*)d_ws;

    const int M = in_sizes[1];           // B*C*D*H*W = 3,145,728
    const int nblocks = (M + BLOCK - 1) / BLOCK;   // 12288

    crps_partial_kernel<<<nblocks, BLOCK, 0, stream>>>(forecasts, target, partial, M);
    crps_final_kernel<<<1, BLOCK, 0, stream>>>(partial, nblocks, out, 1.0f / (float)M);
}